// Round 1
// baseline (1527.296 us; speedup 1.0000x reference)
//
#include <hip/hip_runtime.h>
#include <hip/hip_bf16.h>

typedef __hip_bfloat16 bf16;
typedef _Float16 half_t;
typedef __attribute__((ext_vector_type(8))) _Float16 half8;
typedef __attribute__((ext_vector_type(4))) float f32x4;

#define LN_EPS 1e-5f

static constexpr int Dk     = 256;   // model dim
static constexpr int Tk     = 2048;  // seq len
static constexpr int BTk    = 8192;  // B*T
static constexpr int MHk    = 2048;  // N/H
static constexpr int Nk     = 8192;  // hidden
static constexpr int LAYERS = 6;
static constexpr long long TD  = (long long)Tk * Dk;    // 524288
static constexpr long long BTD = (long long)BTk * Dk;   // 2097152
static constexpr long long TT  = (long long)Tk * Tk;    // 4194304

// LDS k-octet XOR swizzle (verified r10/r11: SQ_LDS_BANK_CONFLICT -> 0).
#define SKQ(t) ((((t) & 3) ^ (((t) >> 3) & 3)) * 8)

// ---------------------------------------------------------------------------
__device__ __forceinline__ float wave_reduce(float v) {
#pragma unroll
    for (int o = 32; o > 0; o >>= 1) v += __shfl_down(v, o);
    return v;
}

__device__ __forceinline__ float block_sum_256(float x, float* sbuf) {
    float s = wave_reduce(x);
    int lane = threadIdx.x & 63, wv = threadIdx.x >> 6;
    if (lane == 0) sbuf[wv] = s;
    __syncthreads();
    float r = sbuf[0] + sbuf[1] + sbuf[2] + sbuf[3];
    __syncthreads();
    return r;
}

__device__ __forceinline__ void glds16(const void* g, void* lds) {
    __builtin_amdgcn_global_load_lds(
        (const __attribute__((address_space(1))) void*)g,
        (__attribute__((address_space(3))) void*)lds, 16, 0, 0);
}

// rope for one row t: thread i<128 handles dims (i, i+128) of nv[256] in LDS
__device__ __forceinline__ void rope_row(const float* nv, int t, half_t* qrow) {
    int i = threadIdx.x;
    if (i < 128) {
        float invf = powf(10000.f, -(float)i / 128.f);
        float ang = (float)t * invf;
        float s, c;
        sincosf(ang, &s, &c);
        float q1 = nv[i], q2 = nv[128 + i];
        qrow[i]       = (half_t)(q1 * c - q2 * s);
        qrow[128 + i] = (half_t)(q2 * c + q1 * s);
    }
}

// ---------------------------------------------------------------------------
// input dtype sniffer (insurance; inputs confirmed fp32)
__global__ __launch_bounds__(256) void sniff_kernel(const unsigned short* __restrict__ w,
                                                    int* __restrict__ flag) {
    __shared__ float sbuf[4];
    int tid = threadIdx.x;
    float cnt = 0.f;
    for (int i = tid; i < 1024; i += 256) {
        int e = (w[i] >> 7) & 0xFF;
        if (e >= 128) cnt += 1.f;
    }
    float tot = block_sum_256(cnt, sbuf);
    if (tid == 0) *flag = (tot > 32.f) ? 1 : 0;
}

// transpose + fp16 convert: src [R][C] (per z) -> dst [C][R] fp16
__global__ __launch_bounds__(256) void tr_cvt16_kernel(const void* __restrict__ src,
                                                       const int* __restrict__ flag,
                                                       half_t* __restrict__ dst,
                                                       int R, int C,
                                                       long long sz, long long dz) {
    __shared__ float t[32][33];
    bool f32 = (*flag != 0);
    int ct = blockIdx.x * 32, rt = blockIdx.y * 32;
    long long so = (long long)blockIdx.z * sz, dofs = (long long)blockIdx.z * dz;
    int tx = threadIdx.x & 31, ty = threadIdx.x >> 5;
#pragma unroll
    for (int i = 0; i < 4; i++) {
        long long idx = so + (long long)(rt + ty + i * 8) * C + ct + tx;
        t[ty + i * 8][tx] = f32 ? ((const float*)src)[idx] : (float)((const bf16*)src)[idx];
    }
    __syncthreads();
#pragma unroll
    for (int i = 0; i < 4; i++) {
        long long odx = dofs + (long long)(ct + ty + i * 8) * R + rt + tx;
        dst[odx] = (half_t)t[tx][ty + i * 8];
    }
}

// v32 [BT][D] fp32 -> vT [D][BT] fp16
__global__ __launch_bounds__(256) void trv_kernel(const float* __restrict__ src,
                                                  half_t* __restrict__ dst) {
    __shared__ float t[32][33];
    int ct = blockIdx.x * 32, rt = blockIdx.y * 32;
    int tx = threadIdx.x & 31, ty = threadIdx.x >> 5;
#pragma unroll
    for (int i = 0; i < 4; i++)
        t[ty + i * 8][tx] = src[(long long)(rt + ty + i * 8) * Dk + ct + tx];
    __syncthreads();
#pragma unroll
    for (int i = 0; i < 4; i++)
        dst[(long long)(ct + ty + i * 8) * BTk + rt + tx] = (half_t)t[tx][ty + i * 8];
}

// ---------------------------------------------------------------------------
// v = layernorm(wte[idx]) -> v32 fp32, vf fp16, qf fp16 (rope fused)
__global__ __launch_bounds__(256) void embed_ln_kernel(const int* __restrict__ idx,
                                                       const void* __restrict__ wte,
                                                       const int* __restrict__ flag,
                                                       float* __restrict__ v,
                                                       half_t* __restrict__ vf,
                                                       half_t* __restrict__ qf) {
    __shared__ float sbuf[4];
    __shared__ float nvs[256];
    int bt = blockIdx.x, tid = threadIdx.x;
    int id = idx[bt];
    bool f32 = (*flag != 0);
    float x = f32 ? ((const float*)wte)[id * Dk + tid]
                  : (float)((const bf16*)wte)[id * Dk + tid];
    float mu = block_sum_256(x, sbuf) * (1.f / 256.f);
    float d = x - mu;
    float var = block_sum_256(d * d, sbuf) * (1.f / 256.f);
    float r = d * rsqrtf(var + LN_EPS);
    v[bt * Dk + tid] = r;
    vf[bt * Dk + tid] = (half_t)r;
    nvs[tid] = r;
    __syncthreads();
    rope_row(nvs, bt & (Tk - 1), qf + (long long)bt * Dk);
}

// lnf = fp16(layernorm(sum of alive a-partials)).
__global__ __launch_bounds__(256) void ln_rows_kernel(const float* __restrict__ Pa,
                                                      half_t* __restrict__ of) {
    __shared__ float sbuf[4];
    int bt = blockIdx.x, tid = threadIdx.x;
    int b = bt >> 11, t = bt & (Tk - 1);
    int ncnt = ((t & ~127) >> 9) + 1;
    const float* p = Pa + ((long long)(b << 2)) * TD + (long long)t * Dk + tid;
    float x = 0.f;
    for (int c = 0; c < ncnt; c++) x += p[(long long)c * TD];
    float mu = block_sum_256(x, sbuf) * (1.f / 256.f);
    float d = x - mu;
    float var = block_sum_256(d * d, sbuf) * (1.f / 256.f);
    float r = d * rsqrtf(var + LN_EPS);
    of[bt * Dk + tid] = (half_t)r;
}

// v += layernorm(sum of 4 update-partials) -> v32, vf, qf (rope fused)
__global__ __launch_bounds__(256) void add_ln_kernel(const float* __restrict__ Pu,
                                                     float* __restrict__ v,
                                                     half_t* __restrict__ vf,
                                                     half_t* __restrict__ qf) {
    __shared__ float sbuf[4];
    __shared__ float nvs[256];
    int bt = blockIdx.x, tid = threadIdx.x;
    long long e = (long long)bt * Dk + tid;
    float x = Pu[e] + Pu[e + BTD] + Pu[e + 2 * BTD] + Pu[e + 3 * BTD];
    float mu = block_sum_256(x, sbuf) * (1.f / 256.f);
    float d = x - mu;
    float var = block_sum_256(d * d, sbuf) * (1.f / 256.f);
    float r = d * rsqrtf(var + LN_EPS);
    float nv = v[e] + r;
    v[e] = nv;
    vf[e] = (half_t)nv;
    nvs[tid] = nv;
    __syncthreads();
    rope_row(nvs, bt & (Tk - 1), qf + (long long)bt * Dk);
}

// ---------------------------------------------------------------------------
// Energy: E[b] = tril(Qr Qr^T), fp16, 128x128 swizzled, z = batch.
__global__ __launch_bounds__(256) void gemm128e(
    const half_t* __restrict__ Q, half_t* __restrict__ E) {
    __shared__ __align__(16) half_t As[128 * 32];
    __shared__ __align__(16) half_t Bs[128 * 32];
    const int tid = threadIdx.x;
    const int lane = tid & 63, wv = tid >> 6;
    const int wr = wv >> 1, wc = wv & 1;
    const int quad = lane >> 4, r = lane & 15;
    const int qsw = (quad ^ ((r >> 1) & 3)) * 8;
    const int mb = blockIdx.y * 128, nb = blockIdx.x * 128;
    if ((int)blockIdx.x > (int)blockIdx.y) return;   // never read
    const half_t* Qb = Q + (long long)blockIdx.z * TD;
    half_t* Eb = E + (long long)blockIdx.z * TT;

    f32x4 acc[4][4] = {};
    const int srow = tid >> 2, skq = SKQ(tid);
    const int wbase = (tid & 192) * 8;
    for (int k0 = 0; k0 < Dk; k0 += 32) {
#pragma unroll
        for (int rnd = 0; rnd < 2; rnd++) {
            int row = rnd * 64 + srow;
            glds16(Qb + (long long)(mb + row) * Dk + k0 + skq, As + rnd * 2048 + wbase);
            glds16(Qb + (long long)(nb + row) * Dk + k0 + skq, Bs + rnd * 2048 + wbase);
        }
        __syncthreads();
        half8 bfr[4];
#pragma unroll
        for (int ni = 0; ni < 4; ni++)
            bfr[ni] = *(const half8*)&Bs[(wc * 64 + ni * 16 + r) * 32 + qsw];
#pragma unroll
        for (int mi = 0; mi < 4; mi++) {
            half8 afr = *(const half8*)&As[(wr * 64 + mi * 16 + r) * 32 + qsw];
#pragma unroll
            for (int ni = 0; ni < 4; ni++)
                acc[mi][ni] = __builtin_amdgcn_mfma_f32_16x16x32_f16(afr, bfr[ni], acc[mi][ni], 0, 0, 0);
        }
        __syncthreads();
    }
#pragma unroll
    for (int mi = 0; mi < 4; mi++)
#pragma unroll
        for (int ni = 0; ni < 4; ni++) {
            int row0 = mb + wr * 64 + mi * 16 + quad * 4;
            int col = nb + wc * 64 + ni * 16 + r;
#pragma unroll
            for (int rr = 0; rr < 4; rr++) {
                int row = row0 + rr;
                float val = (row < col) ? 0.f : acc[mi][ni][rr];
                Eb[(long long)row * Tk + col] = (half_t)val;
            }
        }
}

// ---------------------------------------------------------------------------
// a-GEMM: Pa[z] = E_chunk @ V, 128x128 swizzled, split-K partial stores.
// x = m-tile so blocks sharing an E-panel land on one XCD (r14 win).
__global__ __launch_bounds__(256) void gemm128a(
    const half_t* __restrict__ E, const half_t* __restrict__ vT,
    float* __restrict__ Pa) {
    __shared__ __align__(16) half_t As[128 * 32];
    __shared__ __align__(16) half_t Bs[128 * 32];
    const int tid = threadIdx.x;
    const int lane = tid & 63, wv = tid >> 6;
    const int wr = wv >> 1, wc = wv & 1;
    const int quad = lane >> 4, r = lane & 15;
    const int qsw = (quad ^ ((r >> 1) & 3)) * 8;
    const int mb = blockIdx.x * 128, nb = blockIdx.y * 128;   // swapped
    const int b = blockIdx.z >> 2, c = blockIdx.z & 3;
    const int kbeg = c * 512;
    const int kend = min(mb + 128, kbeg + 512);
    if (kend <= kbeg) return;

    const half_t* Ab = E + (long long)b * TT;
    const half_t* Bb = vT + (long long)b * Tk;
    float* Pc = Pa + (long long)blockIdx.z * TD;
    f32x4 acc[4][4] = {};
    const int srow = tid >> 2, skq = SKQ(tid);
    const int wbase = (tid & 192) * 8;
    for (int k0 = kbeg; k0 < kend; k0 += 32) {
#pragma unroll
        for (int rnd = 0; rnd < 2; rnd++) {
            int row = rnd * 64 + srow;
            glds16(Ab + (long long)(mb + row) * Tk + k0 + skq, As + rnd * 2048 + wbase);
            glds16(Bb + (long long)(nb + row) * BTk + k0 + skq, Bs + rnd * 2048 + wbase);
        }
        __syncthreads();
        half8 bfr[4];
#pragma unroll
        for (int ni = 0; ni < 4; ni++)
            bfr[ni] = *(const half8*)&Bs[(wc * 64 + ni * 16 + r) * 32 + qsw];
#pragma unroll
        for (int mi = 0; mi < 4; mi++) {
            half8 afr = *(const half8*)&As[(wr * 64 + mi * 16 + r) * 32 + qsw];
#pragma unroll
            for (int ni = 0; ni < 4; ni++)
                acc[mi][ni] = __builtin_amdgcn_mfma_f32_16x16x32_f16(afr, bfr[ni], acc[mi][ni], 0, 0, 0);
        }
        __syncthreads();
    }
#pragma unroll
    for (int mi = 0; mi < 4; mi++)
#pragma unroll
        for (int ni = 0; ni < 4; ni++) {
            int row0 = mb + wr * 64 + mi * 16 + quad * 4;
            int col = nb + wc * 64 + ni * 16 + r;
#pragma unroll
            for (int rr = 0; rr < 4; rr++)
                Pc[(long long)(row0 + rr) * Dk + col] = acc[mi][ni][rr];
        }
}

// ---------------------------------------------------------------------------
// Fused dual GEMM + update GEMM (r16): eliminates the y16 HBM round trip
// (131 MB write + ~256 MB read per layer) and the gemm128u dispatch.
// Grid (64 mt x 4 h) = 256 blocks = 1/CU. Per n-subtile (16 per head):
//   phase 1: y = relu(lnf@dyT)*relu(vf@dxT) 128x128 tile (dual_gemm structure)
//   phase 2: y -> swizzled LDS fp16; accU[128 bt][256 d] += y @ eT-chunk
// Pu partial per head h == old gemm128u partial per K-chunk h (same n-range),
// so add_ln is unchanged.
// y_lds swizzle: phys_oct = oct ^ ((row & 12) >> 1) — conflict-free on both
// the b16 write side (8 distinct octets per instr) and b128 read side.
__global__ __launch_bounds__(256, 1) void dual_update(
    const half_t* __restrict__ A1,   // vf  [BT][D]
    const half_t* __restrict__ A2,   // lnf [BT][D]
    const half_t* __restrict__ dxT,  // [Nk][D]
    const half_t* __restrict__ dyT,  // [Nk][D]
    const half_t* __restrict__ eT,   // [D][Nk]
    float* __restrict__ Pu) {        // [4][BT][D] head partials
    __shared__ __align__(16) half_t smem[32768];   // 64 KiB
    half_t* As1 = smem;                 // [128][64] phase-1 staging
    half_t* As2 = smem + 8192;
    half_t* Bs1 = smem + 16384;
    half_t* Bs2 = smem + 24576;
    half_t* yld = smem;                 // [128][128] swizzled (aliases As1+As2)
    half_t* eTs = smem + 16384;         // 2 x [256][32] dbuf (aliases Bs1+Bs2)

    const int tid = threadIdx.x;
    const int lane = tid & 63, wv = tid >> 6;
    const int wr = wv >> 1, wc = wv & 1;          // 2x2 wave grid
    const int quad = lane >> 4, r = lane & 15;
    const int qsw = (quad ^ ((r >> 1) & 3)) * 8;
    // block -> (mt, h): 8 consecutive mt (all 4 h) per XCD for L2 locality
    const int xcd = blockIdx.x & 7, j = blockIdx.x >> 3;
    const int mt = xcd * 8 + (j & 7);             // 0..63
    const int h = j >> 3;                         // 0..3
    const int mb = mt * 128;
    const half_t* B1 = dxT + (long long)h * MHk * Dk;
    const half_t* B2 = dyT + (long long)h * MHk * Dk;
    const half_t* Eh = eT + (long long)h * MHk;   // column offset into [D][Nk]
    float* Pc = Pu + (long long)h * BTD;

    const int srow8 = lane >> 3;                  // phase-1 staging pattern
    const int soct  = (lane & 7) ^ srow8;
    const int srow = tid >> 2, skq = SKQ(tid);    // eT staging pattern
    const int wbase = (tid & 192) * 8;

    f32x4 accU[4][8] = {};                        // [64 bt][128 d] per wave
    for (int nt = 0; nt < 16; ++nt) {
        const int nb = nt * 128;
        // ---------------- phase 1: dual GEMM, y tile in regs ----------------
        f32x4 accX[4][4] = {};
        f32x4 accY[4][4] = {};
        for (int k0 = 0; k0 < Dk; k0 += 64) {
#pragma unroll
            for (int st = 0; st < 4; st++) {
                int row = wv * 32 + st * 8;
                long long ga = (long long)(mb + row + srow8) * Dk + k0 + soct * 8;
                long long gb = (long long)(nb + row + srow8) * Dk + k0 + soct * 8;
                glds16(A1 + ga, As1 + row * 64);
                glds16(A2 + ga, As2 + row * 64);
                glds16(B1 + gb, Bs1 + row * 64);
                glds16(B2 + gb, Bs2 + row * 64);
            }
            __syncthreads();
#pragma unroll
            for (int sub = 0; sub < 2; sub++) {
                half8 b1f[4], b2f[4];
#pragma unroll
                for (int ni = 0; ni < 4; ni++) {
                    int R = wc * 64 + ni * 16 + r;
                    int pos = ((sub * 4 + quad) ^ (R & 7)) * 8;
                    b1f[ni] = *(const half8*)&Bs1[R * 64 + pos];
                    b2f[ni] = *(const half8*)&Bs2[R * 64 + pos];
                }
#pragma unroll
                for (int mi = 0; mi < 4; mi++) {
                    int R = wr * 64 + mi * 16 + r;
                    int pos = ((sub * 4 + quad) ^ (R & 7)) * 8;
                    half8 a1 = *(const half8*)&As1[R * 64 + pos];
                    half8 a2 = *(const half8*)&As2[R * 64 + pos];
#pragma unroll
                    for (int ni = 0; ni < 4; ni++) {
                        accX[mi][ni] = __builtin_amdgcn_mfma_f32_16x16x32_f16(a1, b1f[ni], accX[mi][ni], 0, 0, 0);
                        accY[mi][ni] = __builtin_amdgcn_mfma_f32_16x16x32_f16(a2, b2f[ni], accY[mi][ni], 0, 0, 0);
                    }
                }
            }
            __syncthreads();
        }
        // ------------- y = relu*relu -> swizzled LDS (fp16) -----------------
        // (staging LDS is dead after the loop-final barrier; yld aliases it)
#pragma unroll
        for (int mi = 0; mi < 4; mi++)
#pragma unroll
            for (int ni = 0; ni < 4; ni++) {
                int col = wc * 64 + ni * 16 + r;
                int row0 = wr * 64 + mi * 16 + quad * 4;
#pragma unroll
                for (int rr = 0; rr < 4; rr++) {
                    int W = row0 + rr;
                    float val = fmaxf(accY[mi][ni][rr], 0.f) * fmaxf(accX[mi][ni][rr], 0.f);
                    yld[W * 128 + (((col >> 3) ^ ((W & 12) >> 1)) << 3) + (col & 7)] = (half_t)val;
                }
            }
        // stage eT chunk 0 of this nt (16 KB)
#pragma unroll
        for (int rnd = 0; rnd < 4; rnd++) {
            int row = rnd * 64 + srow;
            glds16(Eh + (long long)row * Nk + nb + skq, eTs + rnd * 2048 + wbase);
        }
        __syncthreads();
        // ---------------- phase 2: accU += y @ eT-chunks --------------------
#pragma unroll
        for (int c = 0; c < 4; ++c) {
            if (c < 3) {
#pragma unroll
                for (int rnd = 0; rnd < 4; rnd++) {
                    int row = rnd * 64 + srow;
                    glds16(Eh + (long long)row * Nk + nb + (c + 1) * 32 + skq,
                           eTs + ((c + 1) & 1) * 8192 + rnd * 2048 + wbase);
                }
            }
            half8 bu[8];
#pragma unroll
            for (int ni = 0; ni < 8; ni++)
                bu[ni] = *(const half8*)&eTs[(c & 1) * 8192 + (wc * 128 + ni * 16 + r) * 32 + qsw];
#pragma unroll
            for (int mi = 0; mi < 4; mi++) {
                int R = wr * 64 + mi * 16 + r;
                half8 au = *(const half8*)&yld[R * 128 + ((((c << 2) + quad) ^ ((R & 12) >> 1)) << 3)];
#pragma unroll
                for (int ni = 0; ni < 8; ni++)
                    accU[mi][ni] = __builtin_amdgcn_mfma_f32_16x16x32_f16(au, bu[ni], accU[mi][ni], 0, 0, 0);
            }
            __syncthreads();   // drains chunk c+1 staging; frees buf for c+2
        }
    }
#pragma unroll
    for (int mi = 0; mi < 4; mi++)
#pragma unroll
        for (int ni = 0; ni < 8; ni++) {
            int row0 = mb + wr * 64 + mi * 16 + quad * 4;
            int col = wc * 128 + ni * 16 + r;
#pragma unroll
            for (int rr = 0; rr < 4; rr++)
                Pc[(long long)(row0 + rr) * Dk + col] = accU[mi][ni][rr];
        }
}

// ---------------------------------------------------------------------------
// Plain fp16 64x64 async GEMM, swizzled, fp32 store — readout.
__global__ __launch_bounds__(256) void gemm64h(
    const half_t* __restrict__ A, int lda,
    const half_t* __restrict__ B, int ldb,
    float* __restrict__ C, int ldc, int K) {
    __shared__ __align__(16) half_t As[64 * 32];
    __shared__ __align__(16) half_t Bs[64 * 32];
    const int tid = threadIdx.x;
    const int lane = tid & 63, wv = tid >> 6;
    const int wr = wv >> 1, wc = wv & 1;
    const int quad = lane >> 4, r = lane & 15;
    const int qsw = (quad ^ ((r >> 1) & 3)) * 8;
    const int mb = blockIdx.y * 64, nb = blockIdx.x * 64;

    f32x4 acc[2][2] = {};
    const int srow = tid >> 2, skq = SKQ(tid);
    const int wbase = (tid & 192) * 8;
    for (int k0 = 0; k0 < K; k0 += 32) {
        glds16(A + (long long)(mb + srow) * lda + k0 + skq, As + wbase);
        glds16(B + (long long)(nb + srow) * ldb + k0 + skq, Bs + wbase);
        __syncthreads();
        half8 b0 = *(const half8*)&Bs[(wc * 32 +  0 + r) * 32 + qsw];
        half8 b1 = *(const half8*)&Bs[(wc * 32 + 16 + r) * 32 + qsw];
#pragma unroll
        for (int mi = 0; mi < 2; mi++) {
            half8 afr = *(const half8*)&As[(wr * 32 + mi * 16 + r) * 32 + qsw];
            acc[mi][0] = __builtin_amdgcn_mfma_f32_16x16x32_f16(afr, b0, acc[mi][0], 0, 0, 0);
            acc[mi][1] = __builtin_amdgcn_mfma_f32_16x16x32_f16(afr, b1, acc[mi][1], 0, 0, 0);
        }
        __syncthreads();
    }
#pragma unroll
    for (int mi = 0; mi < 2; mi++)
#pragma unroll
        for (int ni = 0; ni < 2; ni++) {
            int row0 = mb + wr * 32 + mi * 16 + quad * 4;
            int col = nb + wc * 32 + ni * 16 + r;
#pragma unroll
            for (int rr = 0; rr < 4; rr++)
                C[(long long)(row0 + rr) * ldc + col] = acc[mi][ni][rr];
        }
}

// ---------------------------------------------------------------------------
extern "C" void kernel_launch(void* const* d_in, const int* in_sizes, int n_in,
                              void* d_out, int out_size, void* d_ws, size_t ws_size,
                              hipStream_t stream) {
    (void)in_sizes; (void)n_in; (void)out_size; (void)ws_size;
    const int* idx = (const int*)d_in[0];
    float* out = (float*)d_out;

    char* ws = (char*)d_ws;
    float*  v32  = (float*) (ws);                   //   8 MiB [8192][256]
    half_t* vf   = (half_t*)(ws + (  8ll << 20));   //   4
    half_t* qf   = (half_t*)(ws + ( 12ll << 20));   //   4
    half_t* vT   = (half_t*)(ws + ( 16ll << 20));   //   4 [256][8192]
    half_t* lnf  = (half_t*)(ws + ( 20ll << 20));   //   4
    half_t* E    = (half_t*)(ws + ( 24ll << 20));   //  32 [4][2048][2048] f16
    float*  Pa   = (float*) (ws + ( 56ll << 20));   //  32 [16][2048][256] f32
    float*  Pu   = (float*) (ws + ( 24ll << 20));   //  64 [4][8192][256] f32 (aliases E+Pa, phase-disjoint)
    half_t* dxT  = (half_t*)(ws + (216ll << 20));   //   4 [Nk][D]
    half_t* dyT  = (half_t*)(ws + (220ll << 20));   //   4
    half_t* eT   = (half_t*)(ws + (224ll << 20));   //   4 [256][8192]
    half_t* roT  = (half_t*)(ws + (228ll << 20));   // 128 KiB [256][256]
    int*    flag = (int*)   (ws + (228ll << 20) + (256ll << 10));
    // y16 eliminated (r16 fusion); ws use ~229 MiB of 256

    sniff_kernel<<<1, 256, 0, stream>>>((const unsigned short*)d_in[1], flag);
    tr_cvt16_kernel<<<dim3(MHk / 32, Dk / 32, 4), 256, 0, stream>>>(
        d_in[3], flag, dxT, Dk, MHk, (long long)Dk * MHk, (long long)Dk * MHk);
    tr_cvt16_kernel<<<dim3(MHk / 32, Dk / 32, 4), 256, 0, stream>>>(
        d_in[4], flag, dyT, Dk, MHk, (long long)Dk * MHk, (long long)Dk * MHk);
    tr_cvt16_kernel<<<dim3(Dk / 32, Nk / 32, 1), 256, 0, stream>>>(
        d_in[2], flag, eT, Nk, Dk, 0, 0);
    tr_cvt16_kernel<<<dim3(Dk / 32, Dk / 32, 1), 256, 0, stream>>>(
        d_in[5], flag, roT, Dk, Dk, 0, 0);

    embed_ln_kernel<<<BTk, 256, 0, stream>>>(idx, d_in[1], flag, v32, vf, qf);

    for (int l = 0; l < LAYERS; l++) {
        trv_kernel<<<dim3(Dk / 32, BTk / 32), 256, 0, stream>>>(v32, vT);
        // E[b] = tril(Qr Qr^T), fp16, all 4 batches (upper blocks skipped)
        gemm128e<<<dim3(Tk / 128, Tk / 128, 4), 256, 0, stream>>>(qf, E);
        // Pa[b*4+c] = E_chunk @ v (partials; dead causal chunks skipped)
        gemm128a<<<dim3(Tk / 128, Dk / 128, 16), 256, 0, stream>>>(E, vT, Pa);
        // lnf = LN(sum of alive partials)
        ln_rows_kernel<<<BTk, 256, 0, stream>>>(Pa, lnf);
        // fused: y = relu*relu tiles kept in LDS, Pu[h] = y @ enc (per head)
        dual_update<<<dim3(256), 256, 0, stream>>>(vf, lnf, dxT, dyT, eT, Pu);
        // v += LN(sum of partials); rope fused -> qf for next layer
        add_ln_kernel<<<BTk, 256, 0, stream>>>(Pu, v32, vf, qf);
    }
    // logits = vf @ roT^T -> fp32 out
    gemm64h<<<dim3(Dk / 64, BTk / 64), 256, 0, stream>>>(
        vf, Dk, roT, Dk, out, Dk, Dk);
}

// Round 2
// 1295.378 us; speedup vs baseline: 1.1790x; 1.1790x over previous
//
#include <hip/hip_runtime.h>
#include <hip/hip_bf16.h>

typedef __hip_bfloat16 bf16;
typedef _Float16 half_t;
typedef __attribute__((ext_vector_type(8))) _Float16 half8;
typedef __attribute__((ext_vector_type(4))) float f32x4;

#define LN_EPS 1e-5f

static constexpr int Dk     = 256;   // model dim
static constexpr int Tk     = 2048;  // seq len
static constexpr int BTk    = 8192;  // B*T
static constexpr int MHk    = 2048;  // N/H
static constexpr int Nk     = 8192;  // hidden
static constexpr int LAYERS = 6;
static constexpr long long TD  = (long long)Tk * Dk;    // 524288
static constexpr long long BTD = (long long)BTk * Dk;   // 2097152
static constexpr long long TT  = (long long)Tk * Tk;    // 4194304

// LDS k-octet XOR swizzle (verified r10/r11: SQ_LDS_BANK_CONFLICT -> 0).
#define SKQ(t) ((((t) & 3) ^ (((t) >> 3) & 3)) * 8)

// ---------------------------------------------------------------------------
__device__ __forceinline__ float wave_reduce(float v) {
#pragma unroll
    for (int o = 32; o > 0; o >>= 1) v += __shfl_down(v, o);
    return v;
}

__device__ __forceinline__ float block_sum_256(float x, float* sbuf) {
    float s = wave_reduce(x);
    int lane = threadIdx.x & 63, wv = threadIdx.x >> 6;
    if (lane == 0) sbuf[wv] = s;
    __syncthreads();
    float r = sbuf[0] + sbuf[1] + sbuf[2] + sbuf[3];
    __syncthreads();
    return r;
}

__device__ __forceinline__ void glds16(const void* g, void* lds) {
    __builtin_amdgcn_global_load_lds(
        (const __attribute__((address_space(1))) void*)g,
        (__attribute__((address_space(3))) void*)lds, 16, 0, 0);
}

// rope for one row t: thread i<128 handles dims (i, i+128) of nv[256] in LDS
__device__ __forceinline__ void rope_row(const float* nv, int t, half_t* qrow) {
    int i = threadIdx.x;
    if (i < 128) {
        float invf = powf(10000.f, -(float)i / 128.f);
        float ang = (float)t * invf;
        float s, c;
        sincosf(ang, &s, &c);
        float q1 = nv[i], q2 = nv[128 + i];
        qrow[i]       = (half_t)(q1 * c - q2 * s);
        qrow[128 + i] = (half_t)(q2 * c + q1 * s);
    }
}

// ---------------------------------------------------------------------------
// input dtype sniffer (insurance; inputs confirmed fp32)
__global__ __launch_bounds__(256) void sniff_kernel(const unsigned short* __restrict__ w,
                                                    int* __restrict__ flag) {
    __shared__ float sbuf[4];
    int tid = threadIdx.x;
    float cnt = 0.f;
    for (int i = tid; i < 1024; i += 256) {
        int e = (w[i] >> 7) & 0xFF;
        if (e >= 128) cnt += 1.f;
    }
    float tot = block_sum_256(cnt, sbuf);
    if (tid == 0) *flag = (tot > 32.f) ? 1 : 0;
}

// transpose + fp16 convert: src [R][C] (per z) -> dst [C][R] fp16
__global__ __launch_bounds__(256) void tr_cvt16_kernel(const void* __restrict__ src,
                                                       const int* __restrict__ flag,
                                                       half_t* __restrict__ dst,
                                                       int R, int C,
                                                       long long sz, long long dz) {
    __shared__ float t[32][33];
    bool f32 = (*flag != 0);
    int ct = blockIdx.x * 32, rt = blockIdx.y * 32;
    long long so = (long long)blockIdx.z * sz, dofs = (long long)blockIdx.z * dz;
    int tx = threadIdx.x & 31, ty = threadIdx.x >> 5;
#pragma unroll
    for (int i = 0; i < 4; i++) {
        long long idx = so + (long long)(rt + ty + i * 8) * C + ct + tx;
        t[ty + i * 8][tx] = f32 ? ((const float*)src)[idx] : (float)((const bf16*)src)[idx];
    }
    __syncthreads();
#pragma unroll
    for (int i = 0; i < 4; i++) {
        long long odx = dofs + (long long)(ct + ty + i * 8) * R + rt + tx;
        dst[odx] = (half_t)t[tx][ty + i * 8];
    }
}

// v32 [BT][D] fp32 -> vT [D][BT] fp16
__global__ __launch_bounds__(256) void trv_kernel(const float* __restrict__ src,
                                                  half_t* __restrict__ dst) {
    __shared__ float t[32][33];
    int ct = blockIdx.x * 32, rt = blockIdx.y * 32;
    int tx = threadIdx.x & 31, ty = threadIdx.x >> 5;
#pragma unroll
    for (int i = 0; i < 4; i++)
        t[ty + i * 8][tx] = src[(long long)(rt + ty + i * 8) * Dk + ct + tx];
    __syncthreads();
#pragma unroll
    for (int i = 0; i < 4; i++)
        dst[(long long)(ct + ty + i * 8) * BTk + rt + tx] = (half_t)t[tx][ty + i * 8];
}

// ---------------------------------------------------------------------------
// v = layernorm(wte[idx]) -> v32 fp32, vf fp16, qf fp16 (rope fused)
__global__ __launch_bounds__(256) void embed_ln_kernel(const int* __restrict__ idx,
                                                       const void* __restrict__ wte,
                                                       const int* __restrict__ flag,
                                                       float* __restrict__ v,
                                                       half_t* __restrict__ vf,
                                                       half_t* __restrict__ qf) {
    __shared__ float sbuf[4];
    __shared__ float nvs[256];
    int bt = blockIdx.x, tid = threadIdx.x;
    int id = idx[bt];
    bool f32 = (*flag != 0);
    float x = f32 ? ((const float*)wte)[id * Dk + tid]
                  : (float)((const bf16*)wte)[id * Dk + tid];
    float mu = block_sum_256(x, sbuf) * (1.f / 256.f);
    float d = x - mu;
    float var = block_sum_256(d * d, sbuf) * (1.f / 256.f);
    float r = d * rsqrtf(var + LN_EPS);
    v[bt * Dk + tid] = r;
    vf[bt * Dk + tid] = (half_t)r;
    nvs[tid] = r;
    __syncthreads();
    rope_row(nvs, bt & (Tk - 1), qf + (long long)bt * Dk);
}

// lnf = fp16(layernorm(sum of alive a-partials)).
__global__ __launch_bounds__(256) void ln_rows_kernel(const float* __restrict__ Pa,
                                                      half_t* __restrict__ of) {
    __shared__ float sbuf[4];
    int bt = blockIdx.x, tid = threadIdx.x;
    int b = bt >> 11, t = bt & (Tk - 1);
    int ncnt = ((t & ~127) >> 9) + 1;
    const float* p = Pa + ((long long)(b << 2)) * TD + (long long)t * Dk + tid;
    float x = 0.f;
    for (int c = 0; c < ncnt; c++) x += p[(long long)c * TD];
    float mu = block_sum_256(x, sbuf) * (1.f / 256.f);
    float d = x - mu;
    float var = block_sum_256(d * d, sbuf) * (1.f / 256.f);
    float r = d * rsqrtf(var + LN_EPS);
    of[bt * Dk + tid] = (half_t)r;
}

// v += layernorm(sum of 4 update-partials) -> v32, vf, qf (rope fused)
__global__ __launch_bounds__(256) void add_ln_kernel(const float* __restrict__ Pu,
                                                     float* __restrict__ v,
                                                     half_t* __restrict__ vf,
                                                     half_t* __restrict__ qf) {
    __shared__ float sbuf[4];
    __shared__ float nvs[256];
    int bt = blockIdx.x, tid = threadIdx.x;
    long long e = (long long)bt * Dk + tid;
    float x = Pu[e] + Pu[e + BTD] + Pu[e + 2 * BTD] + Pu[e + 3 * BTD];
    float mu = block_sum_256(x, sbuf) * (1.f / 256.f);
    float d = x - mu;
    float var = block_sum_256(d * d, sbuf) * (1.f / 256.f);
    float r = d * rsqrtf(var + LN_EPS);
    float nv = v[e] + r;
    v[e] = nv;
    vf[e] = (half_t)nv;
    nvs[tid] = nv;
    __syncthreads();
    rope_row(nvs, bt & (Tk - 1), qf + (long long)bt * Dk);
}

// ---------------------------------------------------------------------------
// Energy: E[b] = tril(Qr Qr^T), fp16, 128x128 swizzled, z = batch.
__global__ __launch_bounds__(256) void gemm128e(
    const half_t* __restrict__ Q, half_t* __restrict__ E) {
    __shared__ __align__(16) half_t As[128 * 32];
    __shared__ __align__(16) half_t Bs[128 * 32];
    const int tid = threadIdx.x;
    const int lane = tid & 63, wv = tid >> 6;
    const int wr = wv >> 1, wc = wv & 1;
    const int quad = lane >> 4, r = lane & 15;
    const int qsw = (quad ^ ((r >> 1) & 3)) * 8;
    const int mb = blockIdx.y * 128, nb = blockIdx.x * 128;
    if ((int)blockIdx.x > (int)blockIdx.y) return;   // never read
    const half_t* Qb = Q + (long long)blockIdx.z * TD;
    half_t* Eb = E + (long long)blockIdx.z * TT;

    f32x4 acc[4][4] = {};
    const int srow = tid >> 2, skq = SKQ(tid);
    const int wbase = (tid & 192) * 8;
    for (int k0 = 0; k0 < Dk; k0 += 32) {
#pragma unroll
        for (int rnd = 0; rnd < 2; rnd++) {
            int row = rnd * 64 + srow;
            glds16(Qb + (long long)(mb + row) * Dk + k0 + skq, As + rnd * 2048 + wbase);
            glds16(Qb + (long long)(nb + row) * Dk + k0 + skq, Bs + rnd * 2048 + wbase);
        }
        __syncthreads();
        half8 bfr[4];
#pragma unroll
        for (int ni = 0; ni < 4; ni++)
            bfr[ni] = *(const half8*)&Bs[(wc * 64 + ni * 16 + r) * 32 + qsw];
#pragma unroll
        for (int mi = 0; mi < 4; mi++) {
            half8 afr = *(const half8*)&As[(wr * 64 + mi * 16 + r) * 32 + qsw];
#pragma unroll
            for (int ni = 0; ni < 4; ni++)
                acc[mi][ni] = __builtin_amdgcn_mfma_f32_16x16x32_f16(afr, bfr[ni], acc[mi][ni], 0, 0, 0);
        }
        __syncthreads();
    }
#pragma unroll
    for (int mi = 0; mi < 4; mi++)
#pragma unroll
        for (int ni = 0; ni < 4; ni++) {
            int row0 = mb + wr * 64 + mi * 16 + quad * 4;
            int col = nb + wc * 64 + ni * 16 + r;
#pragma unroll
            for (int rr = 0; rr < 4; rr++) {
                int row = row0 + rr;
                float val = (row < col) ? 0.f : acc[mi][ni][rr];
                Eb[(long long)row * Tk + col] = (half_t)val;
            }
        }
}

// ---------------------------------------------------------------------------
// a-GEMM: Pa[z] = E_chunk @ V, 128x128 swizzled, split-K partial stores.
// x = m-tile so blocks sharing an E-panel land on one XCD (r14 win).
__global__ __launch_bounds__(256) void gemm128a(
    const half_t* __restrict__ E, const half_t* __restrict__ vT,
    float* __restrict__ Pa) {
    __shared__ __align__(16) half_t As[128 * 32];
    __shared__ __align__(16) half_t Bs[128 * 32];
    const int tid = threadIdx.x;
    const int lane = tid & 63, wv = tid >> 6;
    const int wr = wv >> 1, wc = wv & 1;
    const int quad = lane >> 4, r = lane & 15;
    const int qsw = (quad ^ ((r >> 1) & 3)) * 8;
    const int mb = blockIdx.x * 128, nb = blockIdx.y * 128;   // swapped
    const int b = blockIdx.z >> 2, c = blockIdx.z & 3;
    const int kbeg = c * 512;
    const int kend = min(mb + 128, kbeg + 512);
    if (kend <= kbeg) return;

    const half_t* Ab = E + (long long)b * TT;
    const half_t* Bb = vT + (long long)b * Tk;
    float* Pc = Pa + (long long)blockIdx.z * TD;
    f32x4 acc[4][4] = {};
    const int srow = tid >> 2, skq = SKQ(tid);
    const int wbase = (tid & 192) * 8;
    for (int k0 = kbeg; k0 < kend; k0 += 32) {
#pragma unroll
        for (int rnd = 0; rnd < 2; rnd++) {
            int row = rnd * 64 + srow;
            glds16(Ab + (long long)(mb + row) * Tk + k0 + skq, As + rnd * 2048 + wbase);
            glds16(Bb + (long long)(nb + row) * BTk + k0 + skq, Bs + rnd * 2048 + wbase);
        }
        __syncthreads();
        half8 bfr[4];
#pragma unroll
        for (int ni = 0; ni < 4; ni++)
            bfr[ni] = *(const half8*)&Bs[(wc * 64 + ni * 16 + r) * 32 + qsw];
#pragma unroll
        for (int mi = 0; mi < 4; mi++) {
            half8 afr = *(const half8*)&As[(wr * 64 + mi * 16 + r) * 32 + qsw];
#pragma unroll
            for (int ni = 0; ni < 4; ni++)
                acc[mi][ni] = __builtin_amdgcn_mfma_f32_16x16x32_f16(afr, bfr[ni], acc[mi][ni], 0, 0, 0);
        }
        __syncthreads();
    }
#pragma unroll
    for (int mi = 0; mi < 4; mi++)
#pragma unroll
        for (int ni = 0; ni < 4; ni++) {
            int row0 = mb + wr * 64 + mi * 16 + quad * 4;
            int col = nb + wc * 64 + ni * 16 + r;
#pragma unroll
            for (int rr = 0; rr < 4; rr++)
                Pc[(long long)(row0 + rr) * Dk + col] = acc[mi][ni][rr];
        }
}

// ---------------------------------------------------------------------------
// Fused dual GEMM + update GEMM v2 (r17): 512 thr / 8 waves (2x4 grid).
// r16 post-mortem: 4-wave version held accX+accY+accU = 256 acc VGPRs ->
// 240 VGPR -> 1 wave/SIMD -> MfmaUtil 19.7; and yld swizzle ((W&12)>>1)
// left 4-way conflicts (3.1M). Fix: 8 waves split the accumulators
// (64+64 regs/wave, ~190 peak -> 2 waves/SIMD via __launch_bounds__(512,2))
// and yld uses oct ^ (R&7) (8 distinct octets per 16-lane phase -> free).
// Per nt (16 per head): phase 1 y = relu(lnf@dyT)*relu(vf@dxT) 128x128;
// phase 2 y -> swizzled LDS, accU[128 bt][256 d] += y @ eT chunks.
// k-order nt*128+c*32 == old gemm128u k-loop, so Pu/add_ln unchanged.
__global__ __launch_bounds__(512, 2) void dual_update(
    const half_t* __restrict__ A1,   // vf  [BT][D]
    const half_t* __restrict__ A2,   // lnf [BT][D]
    const half_t* __restrict__ dxT,  // [Nk][D]
    const half_t* __restrict__ dyT,  // [Nk][D]
    const half_t* __restrict__ eT,   // [D][Nk]
    float* __restrict__ Pu) {        // [4][BT][D] head partials
    __shared__ __align__(16) half_t smem[32768];   // 64 KiB
    // phase-1 staging: As1=smem, As2=+8192, Bs1=+16384, Bs2=+24576 ([128][64] each)
    half_t* yld = smem;                 // [128][128] swizzled (aliases As1,As2)
    half_t* eTs = smem + 16384;         // 2 x [256][32] dbuf (aliases Bs1,Bs2)

    const int tid = threadIdx.x;
    const int lane = tid & 63, w = tid >> 6;      // 8 waves
    const int wr = w >> 2, wc = w & 3;            // 2 x 4 wave grid
    const int quad = lane >> 4, r = lane & 15;

    // block -> (mt, h): 8 consecutive mt (all 4 h) per XCD for L2 locality
    const int xcd = blockIdx.x & 7, j = blockIdx.x >> 3;
    const int mt = xcd * 8 + (j & 7);             // 0..63
    const int h = j >> 3;                         // 0..3
    const int mb = mt * 128;
    const half_t* B1 = dxT + (long long)h * MHk * Dk;
    const half_t* B2 = dyT + (long long)h * MHk * Dk;
    const half_t* Eh = eT + (long long)h * MHk;   // column offset into [D][Nk]
    float* Pc = Pu + (long long)h * BTD;

    // phase-1 staging: wave pair (w>>1) owns one buffer, 8 rounds x 16 rows.
    // lane covers row (+lane>>3), phys octet lane&7 <- global octet ^(row&7).
    const int bufid = w >> 1, halfsel = w & 1;
    const int srow8 = lane >> 3;
    const int soct = (lane & 7) ^ srow8;
    half_t* sb = smem + bufid * 8192;
    const bool isA = (bufid < 2);
    const half_t* gbase = (bufid == 0) ? A1 : (bufid == 1) ? A2
                        : (bufid == 2) ? B1 : B2;

    // eTs staging (SKQ pattern, rows = tid>>2 per 128-row round)
    const int erow = tid >> 2;
    const int eskq = SKQ(tid);

    f32x4 accU[4][4] = {};                        // [64 bt][64 d] per wave
    for (int nt = 0; nt < 16; ++nt) {
        const int nb = nt * 128;
        const long long gro = isA ? (long long)mb : (long long)nb;
        // ---------------- phase 1: dual GEMM, y tile in regs ----------------
        f32x4 accX[4][2] = {};
        f32x4 accY[4][2] = {};
        for (int k0 = 0; k0 < Dk; k0 += 64) {
#pragma unroll
            for (int t = 0; t < 8; t++) {
                int row = t * 16 + halfsel * 8;
                glds16(gbase + (gro + row + srow8) * Dk + k0 + soct * 8,
                       sb + row * 64);
            }
            __syncthreads();
#pragma unroll
            for (int sub = 0; sub < 2; sub++) {
                half8 b1f[2], b2f[2];
#pragma unroll
                for (int ni = 0; ni < 2; ni++) {
                    int R = wc * 32 + ni * 16 + r;
                    int pos = ((sub * 4 + quad) ^ (R & 7)) * 8;
                    b1f[ni] = *(const half8*)&smem[16384 + R * 64 + pos];
                    b2f[ni] = *(const half8*)&smem[24576 + R * 64 + pos];
                }
#pragma unroll
                for (int mi = 0; mi < 4; mi++) {
                    int R = wr * 64 + mi * 16 + r;
                    int pos = ((sub * 4 + quad) ^ (R & 7)) * 8;
                    half8 a1 = *(const half8*)&smem[R * 64 + pos];
                    half8 a2 = *(const half8*)&smem[8192 + R * 64 + pos];
#pragma unroll
                    for (int ni = 0; ni < 2; ni++) {
                        accX[mi][ni] = __builtin_amdgcn_mfma_f32_16x16x32_f16(a1, b1f[ni], accX[mi][ni], 0, 0, 0);
                        accY[mi][ni] = __builtin_amdgcn_mfma_f32_16x16x32_f16(a2, b2f[ni], accY[mi][ni], 0, 0, 0);
                    }
                }
            }
            __syncthreads();
        }
        // ------------- y = relu*relu -> swizzled LDS (fp16) -----------------
        // phys octet = (col>>3) ^ (W&7): reads spread 8 octets/16-lane phase.
#pragma unroll
        for (int mi = 0; mi < 4; mi++)
#pragma unroll
            for (int ni = 0; ni < 2; ni++) {
                int col = wc * 32 + ni * 16 + r;
                int row0 = wr * 64 + mi * 16 + quad * 4;
#pragma unroll
                for (int rr = 0; rr < 4; rr++) {
                    int W = row0 + rr;
                    float val = fmaxf(accY[mi][ni][rr], 0.f) * fmaxf(accX[mi][ni][rr], 0.f);
                    yld[W * 128 + (((col >> 3) ^ (W & 7)) << 3) + (col & 7)] = (half_t)val;
                }
            }
        // stage eT chunk 0 of this nt (16 KB, 2 rounds of 128 rows)
#pragma unroll
        for (int rd = 0; rd < 2; rd++)
            glds16(Eh + (long long)(rd * 128 + erow) * Nk + nb + eskq,
                   eTs + rd * 4096 + w * 512);
        __syncthreads();
        // ---------------- phase 2: accU += y @ eT-chunks --------------------
#pragma unroll
        for (int c = 0; c < 4; ++c) {
            if (c < 3) {
#pragma unroll
                for (int rd = 0; rd < 2; rd++)
                    glds16(Eh + (long long)(rd * 128 + erow) * Nk + nb + (c + 1) * 32 + eskq,
                           eTs + ((c + 1) & 1) * 8192 + rd * 4096 + w * 512);
            }
            half8 bu[4];
#pragma unroll
            for (int ni = 0; ni < 4; ni++) {
                int d = wc * 64 + ni * 16 + r;
                bu[ni] = *(const half8*)&eTs[(c & 1) * 8192 + d * 32 + ((quad ^ ((r >> 1) & 3)) << 3)];
            }
#pragma unroll
            for (int mi = 0; mi < 4; mi++) {
                int R = wr * 64 + mi * 16 + r;
                half8 au = *(const half8*)&yld[R * 128 + (((c * 4 + quad) ^ (R & 7)) << 3)];
#pragma unroll
                for (int ni = 0; ni < 4; ni++)
                    accU[mi][ni] = __builtin_amdgcn_mfma_f32_16x16x32_f16(au, bu[ni], accU[mi][ni], 0, 0, 0);
            }
            __syncthreads();   // drains prefetch; frees bufs for next c / nt
        }
    }
#pragma unroll
    for (int mi = 0; mi < 4; mi++)
#pragma unroll
        for (int ni = 0; ni < 4; ni++) {
            int row0 = mb + wr * 64 + mi * 16 + quad * 4;
            int col = wc * 64 + ni * 16 + r;
#pragma unroll
            for (int rr = 0; rr < 4; rr++)
                Pc[(long long)(row0 + rr) * Dk + col] = accU[mi][ni][rr];
        }
}

// ---------------------------------------------------------------------------
// Plain fp16 64x64 async GEMM, swizzled, fp32 store — readout.
__global__ __launch_bounds__(256) void gemm64h(
    const half_t* __restrict__ A, int lda,
    const half_t* __restrict__ B, int ldb,
    float* __restrict__ C, int ldc, int K) {
    __shared__ __align__(16) half_t As[64 * 32];
    __shared__ __align__(16) half_t Bs[64 * 32];
    const int tid = threadIdx.x;
    const int lane = tid & 63, wv = tid >> 6;
    const int wr = wv >> 1, wc = wv & 1;
    const int quad = lane >> 4, r = lane & 15;
    const int qsw = (quad ^ ((r >> 1) & 3)) * 8;
    const int mb = blockIdx.y * 64, nb = blockIdx.x * 64;

    f32x4 acc[2][2] = {};
    const int srow = tid >> 2, skq = SKQ(tid);
    const int wbase = (tid & 192) * 8;
    for (int k0 = 0; k0 < K; k0 += 32) {
        glds16(A + (long long)(mb + srow) * lda + k0 + skq, As + wbase);
        glds16(B + (long long)(nb + srow) * ldb + k0 + skq, Bs + wbase);
        __syncthreads();
        half8 b0 = *(const half8*)&Bs[(wc * 32 +  0 + r) * 32 + qsw];
        half8 b1 = *(const half8*)&Bs[(wc * 32 + 16 + r) * 32 + qsw];
#pragma unroll
        for (int mi = 0; mi < 2; mi++) {
            half8 afr = *(const half8*)&As[(wr * 32 + mi * 16 + r) * 32 + qsw];
            acc[mi][0] = __builtin_amdgcn_mfma_f32_16x16x32_f16(afr, b0, acc[mi][0], 0, 0, 0);
            acc[mi][1] = __builtin_amdgcn_mfma_f32_16x16x32_f16(afr, b1, acc[mi][1], 0, 0, 0);
        }
        __syncthreads();
    }
#pragma unroll
    for (int mi = 0; mi < 2; mi++)
#pragma unroll
        for (int ni = 0; ni < 2; ni++) {
            int row0 = mb + wr * 32 + mi * 16 + quad * 4;
            int col = nb + wc * 32 + ni * 16 + r;
#pragma unroll
            for (int rr = 0; rr < 4; rr++)
                C[(long long)(row0 + rr) * ldc + col] = acc[mi][ni][rr];
        }
}

// ---------------------------------------------------------------------------
extern "C" void kernel_launch(void* const* d_in, const int* in_sizes, int n_in,
                              void* d_out, int out_size, void* d_ws, size_t ws_size,
                              hipStream_t stream) {
    (void)in_sizes; (void)n_in; (void)out_size; (void)ws_size;
    const int* idx = (const int*)d_in[0];
    float* out = (float*)d_out;

    char* ws = (char*)d_ws;
    float*  v32  = (float*) (ws);                   //   8 MiB [8192][256]
    half_t* vf   = (half_t*)(ws + (  8ll << 20));   //   4
    half_t* qf   = (half_t*)(ws + ( 12ll << 20));   //   4
    half_t* vT   = (half_t*)(ws + ( 16ll << 20));   //   4 [256][8192]
    half_t* lnf  = (half_t*)(ws + ( 20ll << 20));   //   4
    half_t* E    = (half_t*)(ws + ( 24ll << 20));   //  32 [4][2048][2048] f16
    float*  Pa   = (float*) (ws + ( 56ll << 20));   //  32 [16][2048][256] f32
    float*  Pu   = (float*) (ws + ( 24ll << 20));   //  64 [4][8192][256] f32 (aliases E+Pa, phase-disjoint)
    half_t* dxT  = (half_t*)(ws + (216ll << 20));   //   4 [Nk][D]
    half_t* dyT  = (half_t*)(ws + (220ll << 20));   //   4
    half_t* eT   = (half_t*)(ws + (224ll << 20));   //   4 [256][8192]
    half_t* roT  = (half_t*)(ws + (228ll << 20));   // 128 KiB [256][256]
    int*    flag = (int*)   (ws + (228ll << 20) + (256ll << 10));
    // y16 eliminated (r16 fusion); ws use ~229 MiB of 256

    sniff_kernel<<<1, 256, 0, stream>>>((const unsigned short*)d_in[1], flag);
    tr_cvt16_kernel<<<dim3(MHk / 32, Dk / 32, 4), 256, 0, stream>>>(
        d_in[3], flag, dxT, Dk, MHk, (long long)Dk * MHk, (long long)Dk * MHk);
    tr_cvt16_kernel<<<dim3(MHk / 32, Dk / 32, 4), 256, 0, stream>>>(
        d_in[4], flag, dyT, Dk, MHk, (long long)Dk * MHk, (long long)Dk * MHk);
    tr_cvt16_kernel<<<dim3(Dk / 32, Nk / 32, 1), 256, 0, stream>>>(
        d_in[2], flag, eT, Nk, Dk, 0, 0);
    tr_cvt16_kernel<<<dim3(Dk / 32, Dk / 32, 1), 256, 0, stream>>>(
        d_in[5], flag, roT, Dk, Dk, 0, 0);

    embed_ln_kernel<<<BTk, 256, 0, stream>>>(idx, d_in[1], flag, v32, vf, qf);

    for (int l = 0; l < LAYERS; l++) {
        trv_kernel<<<dim3(Dk / 32, BTk / 32), 256, 0, stream>>>(v32, vT);
        // E[b] = tril(Qr Qr^T), fp16, all 4 batches (upper blocks skipped)
        gemm128e<<<dim3(Tk / 128, Tk / 128, 4), 256, 0, stream>>>(qf, E);
        // Pa[b*4+c] = E_chunk @ v (partials; dead causal chunks skipped)
        gemm128a<<<dim3(Tk / 128, Dk / 128, 16), 256, 0, stream>>>(E, vT, Pa);
        // lnf = LN(sum of alive partials)
        ln_rows_kernel<<<BTk, 256, 0, stream>>>(Pa, lnf);
        // fused: y tiles kept in LDS, Pu[h] = y @ enc (per head), 8 waves
        dual_update<<<dim3(256), 512, 0, stream>>>(vf, lnf, dxT, dyT, eT, Pu);
        // v += LN(sum of partials); rope fused -> qf for next layer
        add_ln_kernel<<<BTk, 256, 0, stream>>>(Pu, v32, vf, qf);
    }
    // logits = vf @ roT^T -> fp32 out
    gemm64h<<<dim3(Dk / 64, BTk / 64), 256, 0, stream>>>(
        vf, Dk, roT, Dk, out, Dk, Dk);
}